// Round 13
// baseline (300.055 us; speedup 1.0000x reference)
//
#include <hip/hip_runtime.h>

#define NB 16
#define NVEC 2048
#define NDIM 32
#define NW 4
#define NHID 128
#define NCLASS 10
#define NG 32               // 64-row chunks per b
#define NSLOT (NG * 2)      // Upart slots per b (each chunk writes 2 m-halves)
#define USIZE (129 * 32)    // U per b: rows 0..127 = fw2@V, row 128 = fb2^T@V

// tanh-approx GELU; validated absmax vs ref in prior sessions.
__device__ __forceinline__ float gelu_fast(float x) {
    float t = 1.5957691216057308f * x * (1.0f + 0.044715f * x * x);
    return x / (1.0f + __expf(-t));
}

// ---------------------------------------------------------------------------
// upart: U-partial for this block's 64 m-rows. Thread (kg,dg,mh) = 8k x 4d
// x 32m (ratio 10.7 FMA/LDS vs R6's 8). The two m-halves write SEPARATE
// Upart slots (no LDS merge, no barriers); k_Ured sums 64 slots.
__device__ __forceinline__ void upart_phase(const float* __restrict__ vs,
                                            const float* __restrict__ fw2s,
                                            const float* __restrict__ fb2l,
                                            int n0, int tid,
                                            float* __restrict__ Up0) {
    int kg = tid & 15, dg = (tid >> 4) & 7, mh = tid >> 7;
    int d0 = dg * 4, mb = mh * 32;
    float* Up = Up0 + (size_t)mh * (NB * USIZE);
    float acc[8][4];
#pragma unroll
    for (int i = 0; i < 8; ++i)
#pragma unroll
        for (int q = 0; q < 4; ++q) acc[i][q] = 0.f;
#pragma unroll
    for (int mt = mb; mt < mb + 32; mt += 4) {
        float4 w[8], v[4];
#pragma unroll
        for (int i = 0; i < 8; ++i)
            w[i] = *(const float4*)&fw2s[(kg + 16 * i) * 68 + mt];   // 2-way=free
#pragma unroll
        for (int q = 0; q < 4; ++q)
            v[q] = *(const float4*)&vs[(mt + q) * 36 + d0];          // 8-addr bcast
#pragma unroll
        for (int i = 0; i < 8; ++i) {
            const float* wf = (const float*)&w[i];
#pragma unroll
            for (int q = 0; q < 4; ++q) {
                float wv = wf[q];
                acc[i][0] += wv * v[q].x; acc[i][1] += wv * v[q].y;
                acc[i][2] += wv * v[q].z; acc[i][3] += wv * v[q].w;
            }
        }
    }
#pragma unroll
    for (int i = 0; i < 8; ++i)
        *(float4*)&Up[(kg + 16 * i) * 32 + d0] =
            make_float4(acc[i][0], acc[i][1], acc[i][2], acc[i][3]);
    int l32 = tid & 127;                 // bias row: each mh sums its 32 m
    if (l32 < 32) {
        float ca = 0.f;
#pragma unroll 8
        for (int mm = 0; mm < 32; ++mm)
            ca += fb2l[n0 + mb + mm] * vs[(mb + mm) * 36 + l32];
        Up[128 * 32 + l32] = ca;
    }
}

// ---------------------------------------------------------------------------
// Embed gather (each emb row read once, full line) + X write + U-partials
// for the first applied layer + out=bias init. grid (NG, NB) x 256.
__global__ __launch_bounds__(256) void k_emb(const int* __restrict__ data,
                                             const float* __restrict__ emb,
                                             const float* __restrict__ fw2l,
                                             const float* __restrict__ fb2l,
                                             const float* __restrict__ bf,
                                             float* __restrict__ X,
                                             float* __restrict__ Upart,
                                             float* __restrict__ out) {
    __shared__ float vs[64 * 36];        // [m][d] pad 36
    __shared__ float fw2s[128 * 68];     // [k][m] pad 68
    int ng = blockIdx.x, b = blockIdx.y, tid = threadIdx.x;
    int n0 = ng * 64;
#pragma unroll
    for (int j = 0; j < 2; ++j) {
        int i = tid + j * 256;
        int r = i >> 3, c4 = (i & 7) * 4;
        int idx = data[b * NVEC + n0 + r];
        float4 v = *(const float4*)&emb[(size_t)idx * NDIM + c4];
        *(float4*)&vs[r * 36 + c4] = v;
        *(float4*)&X[((size_t)b * NVEC + n0 + r) * NDIM + c4] = v;
    }
#pragma unroll
    for (int j = 0; j < 8; ++j) {
        int i = tid + j * 256;
        int k = i >> 4, c4 = (i & 15) * 4;
        *(float4*)&fw2s[k * 68 + c4] =
            *(const float4*)&fw2l[(size_t)k * NVEC + n0 + c4];
    }
    if (ng == 0 && b == 0 && tid < NB * NCLASS)
        out[tid] = bf[tid % NCLASS];
    __syncthreads();
    upart_phase(vs, fw2s, fb2l, n0, tid,
                Upart + ((size_t)(ng * 2) * NB + b) * USIZE);
}

// ---------------------------------------------------------------------------
// Reduce NSLOT=64 partial slots into final U. grid (NB, 5) x 256.
__global__ __launch_bounds__(256) void k_Ured(const float* __restrict__ Upart,
                                              float* __restrict__ U) {
    int b = blockIdx.x;
    int i4 = blockIdx.y * 256 + threadIdx.x;       // USIZE/4 = 1032
    if (i4 >= USIZE / 4) return;
    float4 s = ((const float4*)(Upart + (size_t)b * USIZE))[i4];
#pragma unroll 8
    for (int ms = 1; ms < NSLOT; ++ms) {
        float4 v = ((const float4*)(Upart + ((size_t)ms * NB + b) * USIZE))[i4];
        s.x += v.x; s.y += v.y; s.z += v.z; s.w += v.w;
    }
    ((float4*)(U + (size_t)b * USIZE))[i4] = s;
}

// ---------------------------------------------------------------------------
// Fused layer step (R6 structure, LDS-ratio retiles):
//   h = gelu(X@fw1+b1) [X in regs, 1:8] -> V' = h@U [ks=4, 1:10.7]
//   -> (mid) next-layer U-partials from V' in LDS, or (last) classifier.
// grid (NG, NB) x 256, LDS 77.1 KB -> 2 blocks/CU, launch_bounds(256,2)
// (R9/R10/R12 lesson: cap waves so the allocator isn't squeezed).
template <bool LAST>
__global__ __launch_bounds__(256, 2) void k_apply(const float* __restrict__ X,
                                                  const float* __restrict__ fw1l,
                                                  const float* __restrict__ fb1l,
                                                  const float* __restrict__ U,
                                                  const float* __restrict__ fw2n,
                                                  const float* __restrict__ fb2n,
                                                  float* __restrict__ Upart,
                                                  const float* __restrict__ Wf,
                                                  float* __restrict__ out) {
    __shared__ float xs[64 * 36];        // V' for upart
    __shared__ float w1m[4608];          // w1s[32][132]; then merge [2][64][36]
    __shared__ float hsb[128 * 68];      // h as [64][132-stride]; then fw2n [128][68]
    __shared__ float Us[USIZE];
    int ng = blockIdx.x, b = blockIdx.y, tid = threadIdx.x;
    int n0 = ng * 64;

    // ---- stage w1 [32][132], U; X rows -> registers
#pragma unroll
    for (int jj = 0; jj < 4; ++jj) {
        int i4 = tid + jj * 256;
        int d = i4 >> 5, c4 = (i4 & 31) * 4;
        *(float4*)&w1m[d * 132 + c4] = *(const float4*)&fw1l[d * NHID + c4];
    }
    for (int i4 = tid; i4 < USIZE / 4; i4 += 256)
        ((float4*)Us)[i4] = ((const float4*)(U + (size_t)b * USIZE))[i4];
    int rg5 = tid & 31, kg5 = tid >> 5, k0 = kg5 * 16;
    float xr[2][32];
    {
        const float4* X0 = (const float4*)(X + ((size_t)b * NVEC + n0 + rg5) * NDIM);
        const float4* X1 = (const float4*)(X + ((size_t)b * NVEC + n0 + rg5 + 32) * NDIM);
#pragma unroll
        for (int j = 0; j < 8; ++j) {
            float4 v0 = X0[j], v1 = X1[j];
            xr[0][4 * j] = v0.x; xr[0][4 * j + 1] = v0.y;
            xr[0][4 * j + 2] = v0.z; xr[0][4 * j + 3] = v0.w;
            xr[1][4 * j] = v1.x; xr[1][4 * j + 1] = v1.y;
            xr[1][4 * j + 2] = v1.z; xr[1][4 * j + 3] = v1.w;
        }
    }
    __syncthreads();

    {   // ---- h: rows {rg5, rg5+32} x 16 k; X from regs, w1 broadcast from LDS
        float hacc[2][16];
        {
            float4 bq[4];
#pragma unroll
            for (int q = 0; q < 4; ++q) bq[q] = *(const float4*)&fb1l[k0 + 4 * q];
#pragma unroll
            for (int q = 0; q < 4; ++q) {
                hacc[0][4 * q] = bq[q].x; hacc[0][4 * q + 1] = bq[q].y;
                hacc[0][4 * q + 2] = bq[q].z; hacc[0][4 * q + 3] = bq[q].w;
                hacc[1][4 * q] = bq[q].x; hacc[1][4 * q + 1] = bq[q].y;
                hacc[1][4 * q + 2] = bq[q].z; hacc[1][4 * q + 3] = bq[q].w;
            }
        }
#pragma unroll
        for (int d = 0; d < NDIM; ++d) {
            const float* wrow = &w1m[d * 132 + k0];          // 2-addr broadcast
            float4 w0 = *(const float4*)wrow;
            float4 w1 = *(const float4*)(wrow + 4);
            float4 w2 = *(const float4*)(wrow + 8);
            float4 w3 = *(const float4*)(wrow + 12);
            float wk[16] = {w0.x, w0.y, w0.z, w0.w, w1.x, w1.y, w1.z, w1.w,
                            w2.x, w2.y, w2.z, w2.w, w3.x, w3.y, w3.z, w3.w};
            float x0 = xr[0][d], x1 = xr[1][d];
#pragma unroll
            for (int q = 0; q < 16; ++q) {
                hacc[0][q] += x0 * wk[q];
                hacc[1][q] += x1 * wk[q];
            }
        }
#pragma unroll
        for (int r = 0; r < 2; ++r) {
            int row = rg5 + 32 * r;
#pragma unroll
            for (int q4 = 0; q4 < 4; ++q4) {
                float4 o;
                o.x = gelu_fast(hacc[r][4 * q4]);     o.y = gelu_fast(hacc[r][4 * q4 + 1]);
                o.z = gelu_fast(hacc[r][4 * q4 + 2]); o.w = gelu_fast(hacc[r][4 * q4 + 3]);
                *(float4*)&hsb[row * 132 + k0 + 4 * q4] = o;
            }
        }
    }
    __syncthreads();

    // ---- apply: thread (rg, dg, kseg) = 4r x 8d x 32k (kseg wave-aligned)
    int rg = tid & 15, dg = (tid >> 4) & 3, kseg = tid >> 6;
    int d0 = dg * 8, kb = kseg * 32;
    float a[4][8];
#pragma unroll
    for (int i = 0; i < 4; ++i)
#pragma unroll
        for (int q = 0; q < 8; ++q) a[i][q] = 0.f;
#pragma unroll
    for (int ks = kb; ks < kb + 32; ks += 4) {
        float4 h[4];
#pragma unroll
        for (int i = 0; i < 4; ++i)
            h[i] = *(const float4*)&hsb[(rg + 16 * i) * 132 + ks];   // 2-way=free
        float4 u[4][2];
#pragma unroll
        for (int q = 0; q < 4; ++q) {
            u[q][0] = *(const float4*)&Us[(ks + q) * 32 + d0];       // 4-addr bcast
            u[q][1] = *(const float4*)&Us[(ks + q) * 32 + d0 + 4];
        }
#pragma unroll
        for (int i = 0; i < 4; ++i) {
            const float* hf = (const float*)&h[i];
#pragma unroll
            for (int q = 0; q < 4; ++q) {
                float hv = hf[q];
                a[i][0] += hv * u[q][0].x; a[i][1] += hv * u[q][0].y;
                a[i][2] += hv * u[q][0].z; a[i][3] += hv * u[q][0].w;
                a[i][4] += hv * u[q][1].x; a[i][5] += hv * u[q][1].y;
                a[i][6] += hv * u[q][1].z; a[i][7] += hv * u[q][1].w;
            }
        }
    }
    __syncthreads();                     // sync1: hsb/w1m reads done
    float* mb0 = w1m;                    // [64][36]
    float* mb1 = w1m + 2304;             // [64][36]
    if (kseg == 1) {
#pragma unroll
        for (int i = 0; i < 4; ++i) {
            float* p = &mb0[(rg + 16 * i) * 36 + d0];
            *(float4*)p       = make_float4(a[i][0], a[i][1], a[i][2], a[i][3]);
            *(float4*)(p + 4) = make_float4(a[i][4], a[i][5], a[i][6], a[i][7]);
        }
    } else if (kseg == 3) {
#pragma unroll
        for (int i = 0; i < 4; ++i) {
            float* p = &mb1[(rg + 16 * i) * 36 + d0];
            *(float4*)p       = make_float4(a[i][0], a[i][1], a[i][2], a[i][3]);
            *(float4*)(p + 4) = make_float4(a[i][4], a[i][5], a[i][6], a[i][7]);
        }
    }
    __syncthreads();                     // sync2
    if constexpr (!LAST) {               // stage next-layer fw2 into hsb
#pragma unroll
        for (int jj = 0; jj < 8; ++jj) {
            int i4 = tid + jj * 256;
            int k = i4 >> 4, c4 = (i4 & 15) * 4;
            *(float4*)&hsb[k * 68 + c4] =
                *(const float4*)&fw2n[(size_t)k * NVEC + n0 + c4];
        }
    }
    if (kseg == 0) {
#pragma unroll
        for (int i = 0; i < 4; ++i) {
            const float* p = &mb0[(rg + 16 * i) * 36 + d0];
            float4 p0 = *(const float4*)p, p1 = *(const float4*)(p + 4);
            a[i][0] += p0.x; a[i][1] += p0.y; a[i][2] += p0.z; a[i][3] += p0.w;
            a[i][4] += p1.x; a[i][5] += p1.y; a[i][6] += p1.z; a[i][7] += p1.w;
        }
    } else if (kseg == 2) {
#pragma unroll
        for (int i = 0; i < 4; ++i) {
            float* p = &mb1[(rg + 16 * i) * 36 + d0];
            float4 p0 = *(const float4*)p, p1 = *(const float4*)(p + 4);
            a[i][0] += p0.x; a[i][1] += p0.y; a[i][2] += p0.z; a[i][3] += p0.w;
            a[i][4] += p1.x; a[i][5] += p1.y; a[i][6] += p1.z; a[i][7] += p1.w;
            *(float4*)p       = make_float4(a[i][0], a[i][1], a[i][2], a[i][3]);
            *(float4*)(p + 4) = make_float4(a[i][4], a[i][5], a[i][6], a[i][7]);
        }
    }
    __syncthreads();                     // sync3
    if (kseg == 0) {                     // final merge + U bias row
        float4 ub0 = *(const float4*)&Us[128 * 32 + d0];
        float4 ub1 = *(const float4*)&Us[128 * 32 + d0 + 4];
#pragma unroll
        for (int i = 0; i < 4; ++i) {
            const float* p = &mb1[(rg + 16 * i) * 36 + d0];
            float4 p0 = *(const float4*)p, p1 = *(const float4*)(p + 4);
            a[i][0] += p0.x + ub0.x; a[i][1] += p0.y + ub0.y;
            a[i][2] += p0.z + ub0.z; a[i][3] += p0.w + ub0.w;
            a[i][4] += p1.x + ub1.x; a[i][5] += p1.y + ub1.y;
            a[i][6] += p1.z + ub1.z; a[i][7] += p1.w + ub1.w;
            if constexpr (!LAST) {
                float* pv = &xs[(rg + 16 * i) * 36 + d0];
                *(float4*)pv       = make_float4(a[i][0], a[i][1], a[i][2], a[i][3]);
                *(float4*)(pv + 4) = make_float4(a[i][4], a[i][5], a[i][6], a[i][7]);
            }
        }
    }
    if constexpr (LAST) {
        // classifier from kseg0's merged V' rows; other waves contribute 0
        float accC[NCLASS];
#pragma unroll
        for (int c = 0; c < NCLASS; ++c) accC[c] = 0.f;
        if (kseg == 0) {
#pragma unroll
            for (int i = 0; i < 4; ++i) {
                int nrow = n0 + rg + 16 * i;
#pragma unroll
                for (int dd = 0; dd < 8; ++dd) {
                    float v = a[i][dd];
                    const float2* wr =
                        (const float2*)(Wf + ((size_t)nrow * 32 + d0 + dd) * NCLASS);
#pragma unroll
                    for (int p5 = 0; p5 < 5; ++p5) {
                        float2 w = wr[p5];
                        accC[2 * p5]     += v * w.x;
                        accC[2 * p5 + 1] += v * w.y;
                    }
                }
            }
#pragma unroll
            for (int c = 0; c < NCLASS; ++c)
#pragma unroll
                for (int off = 32; off >= 1; off >>= 1)
                    accC[c] += __shfl_down(accC[c], off, 64);
            if (tid == 0) {
#pragma unroll
                for (int c = 0; c < NCLASS; ++c)
                    atomicAdd(&out[b * NCLASS + c], accC[c]);
            }
        }
    } else {
        __syncthreads();                 // sync4: V' (xs) + fw2n (hsb) ready
        upart_phase(xs, hsb, fb2n, n0, tid,
                    Upart + ((size_t)(ng * 2) * NB + b) * USIZE);
    }
}

// ---------------------------------------------------------------------------
extern "C" void kernel_launch(void* const* d_in, const int* in_sizes, int n_in,
                              void* d_out, int out_size, void* d_ws, size_t ws_size,
                              hipStream_t stream) {
    const int*   data = (const int*)d_in[0];
    const float* emb  = (const float*)d_in[1];
    const float* fw1  = (const float*)d_in[2];
    const float* fb1  = (const float*)d_in[3];
    const float* fw2  = (const float*)d_in[4];
    const float* fb2  = (const float*)d_in[5];
    const float* Wf   = (const float*)d_in[6];
    const float* bf   = (const float*)d_in[7];
    float* out = (float*)d_out;

    float* X     = (float*)d_ws;                        // 1,048,576 floats
    float* Upart = X + (size_t)NB * NVEC * NDIM;        // NSLOT*NB*USIZE = 4,227,072
    float* U     = Upart + (size_t)NSLOT * NB * USIZE;  // NB*USIZE = 66,048

    k_emb<<<dim3(NG, NB), 256, 0, stream>>>(data, emb, fw2 + 3 * (size_t)NHID * NVEC,
                                            fb2 + 3 * (size_t)NVEC, bf, X, Upart, out);
    k_Ured<<<dim3(NB, 5), 256, 0, stream>>>(Upart, U);

    for (int i = NW - 1; i >= 1; --i) {
        k_apply<false><<<dim3(NG, NB), 256, 0, stream>>>(
            X, fw1 + (size_t)i * NDIM * NHID, fb1 + (size_t)i * NHID, U,
            fw2 + (size_t)(i - 1) * NHID * NVEC, fb2 + (size_t)(i - 1) * NVEC,
            Upart, nullptr, nullptr);
        k_Ured<<<dim3(NB, 5), 256, 0, stream>>>(Upart, U);
    }
    k_apply<true><<<dim3(NG, NB), 256, 0, stream>>>(
        X, fw1, fb1, U, nullptr, nullptr, nullptr, Wf, out);
}

// Round 14
// 177.584 us; speedup vs baseline: 1.6896x; 1.6896x over previous
//
#include <hip/hip_runtime.h>

#define NB 16
#define NVEC 2048
#define NDIM 32
#define NW 4
#define NHID 128
#define NCLASS 10
#define NG 32               // 64-row chunks per b = U-partial slots
#define USIZE (129 * 32)    // U per b: rows 0..127 = fw2@V, row 128 = fb2^T@V

// tanh-approx GELU; validated absmax vs ref in prior sessions.
__device__ __forceinline__ float gelu_fast(float x) {
    float t = 1.5957691216057308f * x * (1.0f + 0.044715f * x * x);
    return x / (1.0f + __expf(-t));
}

// ---------------------------------------------------------------------------
// Phase C (shared): Upart[k][d] += fw2s[k][m] * vs[m][d] over this block's
// 64 m-rows; bias row from fb2 (global, uniform) * vs. Thread = 4k(interleaved,
// kg=lane-contig -> 2-way max on fw2s stride-68 rows) x 4d (vs broadcast).
// 8 LDS instr per 64 FMA-instr.
__device__ __forceinline__ void upart_phase(const float* __restrict__ vs,
                                            const float* __restrict__ fw2s,
                                            const float* __restrict__ fb2l,
                                            int n0, int tid,
                                            float* __restrict__ Up) {
    int kg = tid & 31, d0 = (tid >> 5) * 4;
    float acc[4][4];
#pragma unroll
    for (int i = 0; i < 4; ++i)
#pragma unroll
        for (int j = 0; j < 4; ++j) acc[i][j] = 0.f;
#pragma unroll 4
    for (int mm = 0; mm < 64; mm += 4) {
        float4 w[4], v[4];
#pragma unroll
        for (int i = 0; i < 4; ++i)
            w[i] = *(const float4*)&fw2s[(kg + 32 * i) * 68 + mm];
#pragma unroll
        for (int j = 0; j < 4; ++j)
            v[j] = *(const float4*)&vs[(mm + j) * 36 + d0];
#pragma unroll
        for (int i = 0; i < 4; ++i) {
            const float* wf = (const float*)&w[i];
#pragma unroll
            for (int j = 0; j < 4; ++j) {
                float wv = wf[j];
                acc[i][0] += wv * v[j].x; acc[i][1] += wv * v[j].y;
                acc[i][2] += wv * v[j].z; acc[i][3] += wv * v[j].w;
            }
        }
    }
#pragma unroll
    for (int i = 0; i < 4; ++i)
        *(float4*)&Up[(kg + 32 * i) * 32 + d0] =
            make_float4(acc[i][0], acc[i][1], acc[i][2], acc[i][3]);
    if (tid < 32) {
        float ca = 0.f;
#pragma unroll 8
        for (int mm = 0; mm < 64; ++mm)
            ca += fb2l[n0 + mm] * vs[mm * 36 + tid];
        Up[128 * 32 + tid] = ca;
    }
}

// ---------------------------------------------------------------------------
// Embed gather (each emb row read ONCE, full 128B line -- R5 post-mortem:
// chunked re-gather cost ~1GB of L2 transactions) + X write + U-partials for
// the FIRST applied layer (fw2[3] @ X) + out=bias init. grid (NG, NB) x 256.
__global__ __launch_bounds__(256) void k_emb(const int* __restrict__ data,
                                             const float* __restrict__ emb,
                                             const float* __restrict__ fw2l,
                                             const float* __restrict__ fb2l,
                                             const float* __restrict__ bf,
                                             float* __restrict__ X,
                                             float* __restrict__ Upart,
                                             float* __restrict__ out) {
    __shared__ float vs[64 * 36];        // [m][d] pad 36
    __shared__ float fw2s[128 * 68];     // [k][m] pad 68
    int ng = blockIdx.x, b = blockIdx.y, tid = threadIdx.x;
    int n0 = ng * 64;
#pragma unroll
    for (int j = 0; j < 2; ++j) {
        int i = tid + j * 256;
        int r = i >> 3, c4 = (i & 7) * 4;
        int idx = data[b * NVEC + n0 + r];
        float4 v = *(const float4*)&emb[(size_t)idx * NDIM + c4];
        *(float4*)&vs[r * 36 + c4] = v;
        *(float4*)&X[((size_t)b * NVEC + n0 + r) * NDIM + c4] = v;
    }
#pragma unroll
    for (int j = 0; j < 8; ++j) {
        int i = tid + j * 256;
        int k = i >> 4, c4 = (i & 15) * 4;
        *(float4*)&fw2s[k * 68 + c4] =
            *(const float4*)&fw2l[(size_t)k * NVEC + n0 + c4];
    }
    if (ng == 0 && b == 0 && tid < NB * NCLASS)
        out[tid] = bf[tid % NCLASS];
    __syncthreads();
    upart_phase(vs, fw2s, fb2l, n0, tid, Upart + ((size_t)ng * NB + b) * USIZE);
}

// ---------------------------------------------------------------------------
// Reduce NG partial slots into final U. grid (NB, 5) x 256. Independent loads.
__global__ __launch_bounds__(256) void k_Ured(const float* __restrict__ Upart,
                                              float* __restrict__ U) {
    int b = blockIdx.x;
    int i4 = blockIdx.y * 256 + threadIdx.x;       // USIZE/4 = 1032
    if (i4 >= USIZE / 4) return;
    float4 s = ((const float4*)(Upart + (size_t)b * USIZE))[i4];
#pragma unroll
    for (int ms = 1; ms < NG; ++ms) {
        float4 v = ((const float4*)(Upart + ((size_t)ms * NB + b) * USIZE))[i4];
        s.x += v.x; s.y += v.y; s.z += v.z; s.w += v.w;
    }
    ((float4*)(U + (size_t)b * USIZE))[i4] = s;
}

// ---------------------------------------------------------------------------
// Fused layer step: h = gelu(X@fw1+b1) -> V' = h@U + ub -> (mid) next-layer
// U-partials from V' IN LDS (V' never touches global!) or (last) classifier.
// grid (NG, NB) x 256, LDS 75.8 KB -> 2 blocks/CU, 8 waves.
template <bool LAST>
__global__ __launch_bounds__(256) void k_apply(const float* __restrict__ X,
                                               const float* __restrict__ fw1l,
                                               const float* __restrict__ fb1l,
                                               const float* __restrict__ U,
                                               const float* __restrict__ fw2n,
                                               const float* __restrict__ fb2n,
                                               float* __restrict__ Upart,
                                               const float* __restrict__ Wf,
                                               float* __restrict__ out) {
    __shared__ float xs[64 * 36];        // X rows; then merge buf; then V'
    __shared__ float w1s[32 * 132];      // [d][k] pad 132
    __shared__ float hsb[128 * 68];      // h as [64r][132k-stride]; then fw2n [128][68]
    __shared__ float Us[USIZE];          // U linear, broadcast reads
    __shared__ float ored[4][NCLASS];
    int ng = blockIdx.x, b = blockIdx.y, tid = threadIdx.x;
    int n0 = ng * 64;

    // ---- stage X rows, w1, U
#pragma unroll
    for (int j = 0; j < 2; ++j) {
        int i = tid + j * 256;
        int r = i >> 3, c4 = (i & 7) * 4;
        *(float4*)&xs[r * 36 + c4] =
            *(const float4*)&X[((size_t)b * NVEC + n0 + r) * NDIM + c4];
    }
#pragma unroll
    for (int j = 0; j < 4; ++j) {
        int i = tid + j * 256;
        int d = i >> 5, c4 = (i & 31) * 4;
        *(float4*)&w1s[d * 132 + c4] = *(const float4*)&fw1l[d * NHID + c4];
    }
    for (int i4 = tid; i4 < USIZE / 4; i4 += 256)
        ((float4*)Us)[i4] = ((const float4*)(U + (size_t)b * USIZE))[i4];
    __syncthreads();

    int rg = tid & 31;                       // lane-contiguous row id
    {   // ---- h: thread = rows {rg, rg+32} x 16 k (k0 uniform per half-wave)
        int k0 = (tid >> 5) * 16;
        float acc[2][16];
        {
            float4 bq[4];
#pragma unroll
            for (int q = 0; q < 4; ++q) bq[q] = *(const float4*)&fb1l[k0 + 4 * q];
#pragma unroll
            for (int q = 0; q < 4; ++q) {
                acc[0][4 * q + 0] = bq[q].x; acc[0][4 * q + 1] = bq[q].y;
                acc[0][4 * q + 2] = bq[q].z; acc[0][4 * q + 3] = bq[q].w;
                acc[1][4 * q + 0] = bq[q].x; acc[1][4 * q + 1] = bq[q].y;
                acc[1][4 * q + 2] = bq[q].z; acc[1][4 * q + 3] = bq[q].w;
            }
        }
#pragma unroll 4
        for (int d = 0; d < NDIM; ++d) {
            float x0 = xs[rg * 36 + d];
            float x1 = xs[(rg + 32) * 36 + d];
            const float* wrow = &w1s[d * 132 + k0];          // broadcast
            float4 w0 = *(const float4*)wrow;
            float4 w1 = *(const float4*)(wrow + 4);
            float4 w2 = *(const float4*)(wrow + 8);
            float4 w3 = *(const float4*)(wrow + 12);
            float wk[16] = {w0.x, w0.y, w0.z, w0.w, w1.x, w1.y, w1.z, w1.w,
                            w2.x, w2.y, w2.z, w2.w, w3.x, w3.y, w3.z, w3.w};
#pragma unroll
            for (int j = 0; j < 16; ++j) {
                acc[0][j] += x0 * wk[j];
                acc[1][j] += x1 * wk[j];
            }
        }
#pragma unroll
        for (int r = 0; r < 2; ++r) {
            int row = rg + 32 * r;
#pragma unroll
            for (int q = 0; q < 4; ++q) {
                float4 o;
                o.x = gelu_fast(acc[r][4 * q + 0]);
                o.y = gelu_fast(acc[r][4 * q + 1]);
                o.z = gelu_fast(acc[r][4 * q + 2]);
                o.w = gelu_fast(acc[r][4 * q + 3]);
                *(float4*)&hsb[row * 132 + k0 + 4 * q] = o;
            }
        }
    }
    __syncthreads();

    // ---- apply: thread = rows {rg, rg+32} x 8 d x k-half
    int dg = (tid >> 5) & 3, kh = tid >> 7;
    int d0 = dg * 8, kb = kh * 64;
    float a[2][8];
#pragma unroll
    for (int r = 0; r < 2; ++r)
#pragma unroll
        for (int j = 0; j < 8; ++j) a[r][j] = 0.f;
#pragma unroll 4
    for (int ks = 0; ks < 64; ks += 4) {
        int kk = kb + ks;
        float4 h0 = *(const float4*)&hsb[rg * 132 + kk];
        float4 h1 = *(const float4*)&hsb[(rg + 32) * 132 + kk];
        float4 u[4][2];
#pragma unroll
        for (int j = 0; j < 4; ++j) {
            u[j][0] = *(const float4*)&Us[(kk + j) * 32 + d0];       // broadcast
            u[j][1] = *(const float4*)&Us[(kk + j) * 32 + d0 + 4];
        }
        const float* hf0 = (const float*)&h0;
        const float* hf1 = (const float*)&h1;
#pragma unroll
        for (int j = 0; j < 4; ++j) {
            float v0 = hf0[j], v1 = hf1[j];
            a[0][0] += v0 * u[j][0].x; a[0][1] += v0 * u[j][0].y;
            a[0][2] += v0 * u[j][0].z; a[0][3] += v0 * u[j][0].w;
            a[0][4] += v0 * u[j][1].x; a[0][5] += v0 * u[j][1].y;
            a[0][6] += v0 * u[j][1].z; a[0][7] += v0 * u[j][1].w;
            a[1][0] += v1 * u[j][0].x; a[1][1] += v1 * u[j][0].y;
            a[1][2] += v1 * u[j][0].z; a[1][3] += v1 * u[j][0].w;
            a[1][4] += v1 * u[j][1].x; a[1][5] += v1 * u[j][1].y;
            a[1][6] += v1 * u[j][1].z; a[1][7] += v1 * u[j][1].w;
        }
    }
    if (kh == 1) {   // publish k-half-1 partials (xs dead after h)
#pragma unroll
        for (int r = 0; r < 2; ++r) {
            float* p = &xs[(rg + 32 * r) * 36 + d0];
            *(float4*)p       = make_float4(a[r][0], a[r][1], a[r][2], a[r][3]);
            *(float4*)(p + 4) = make_float4(a[r][4], a[r][5], a[r][6], a[r][7]);
        }
    }
    __syncthreads();                         // apply reads of hsb done too

    if constexpr (!LAST) {                   // stage next-layer fw2 into hsb
#pragma unroll
        for (int j = 0; j < 8; ++j) {
            int i = tid + j * 256;
            int k = i >> 4, c4 = (i & 15) * 4;
            *(float4*)&hsb[k * 68 + c4] =
                *(const float4*)&fw2n[(size_t)k * NVEC + n0 + c4];
        }
    }
    if (kh == 0) {   // merge halves + U bias row -> final V' into xs
        float4 ub0 = *(const float4*)&Us[128 * 32 + d0];
        float4 ub1 = *(const float4*)&Us[128 * 32 + d0 + 4];
#pragma unroll
        for (int r = 0; r < 2; ++r) {
            float* p = &xs[(rg + 32 * r) * 36 + d0];
            float4 p0 = *(const float4*)p;
            float4 p1 = *(const float4*)(p + 4);
            a[r][0] += p0.x + ub0.x; a[r][1] += p0.y + ub0.y;
            a[r][2] += p0.z + ub0.z; a[r][3] += p0.w + ub0.w;
            a[r][4] += p1.x + ub1.x; a[r][5] += p1.y + ub1.y;
            a[r][6] += p1.z + ub1.z; a[r][7] += p1.w + ub1.w;
            *(float4*)p       = make_float4(a[r][0], a[r][1], a[r][2], a[r][3]);
            *(float4*)(p + 4) = make_float4(a[r][4], a[r][5], a[r][6], a[r][7]);
        }
    }
    __syncthreads();                         // V' (xs) + fw2s (hsb) ready

    if constexpr (!LAST) {
        upart_phase(xs, hsb, fb2n, n0, tid,
                    Upart + ((size_t)ng * NB + b) * USIZE);
    } else {
        // classifier: out[b,c] += sum V'[n,d] * Wf[n*32+d, c]
        float accC[NCLASS];
#pragma unroll
        for (int c = 0; c < NCLASS; ++c) accC[c] = 0.f;
        if (kh == 0) {
#pragma unroll
            for (int r = 0; r < 2; ++r) {
                int nrow = n0 + rg + 32 * r;
#pragma unroll
                for (int dd = 0; dd < 8; ++dd) {
                    float v = a[r][dd];
                    const float2* wr =
                        (const float2*)(Wf + ((size_t)nrow * 32 + d0 + dd) * NCLASS);
#pragma unroll
                    for (int p = 0; p < 5; ++p) {
                        float2 w = wr[p];
                        accC[2 * p]     += v * w.x;
                        accC[2 * p + 1] += v * w.y;
                    }
                }
            }
        }
#pragma unroll
        for (int c = 0; c < NCLASS; ++c)
#pragma unroll
            for (int off = 32; off >= 1; off >>= 1)
                accC[c] += __shfl_down(accC[c], off, 64);
        int w = tid >> 6;
        if ((tid & 63) == 0) {
#pragma unroll
            for (int c = 0; c < NCLASS; ++c) ored[w][c] = accC[c];
        }
        __syncthreads();
        if (tid < NCLASS)
            atomicAdd(&out[b * NCLASS + tid],
                      ored[0][tid] + ored[1][tid] + ored[2][tid] + ored[3][tid]);
    }
}

// ---------------------------------------------------------------------------
extern "C" void kernel_launch(void* const* d_in, const int* in_sizes, int n_in,
                              void* d_out, int out_size, void* d_ws, size_t ws_size,
                              hipStream_t stream) {
    const int*   data = (const int*)d_in[0];
    const float* emb  = (const float*)d_in[1];
    const float* fw1  = (const float*)d_in[2];
    const float* fb1  = (const float*)d_in[3];
    const float* fw2  = (const float*)d_in[4];
    const float* fb2  = (const float*)d_in[5];
    const float* Wf   = (const float*)d_in[6];
    const float* bf   = (const float*)d_in[7];
    float* out = (float*)d_out;

    float* X     = (float*)d_ws;                      // 1048576 floats
    float* Upart = X + (size_t)NB * NVEC * NDIM;      // NG*NB*USIZE = 2113536
    float* U     = Upart + (size_t)NG * NB * USIZE;   // NB*USIZE = 66048

    // embed + X + U-partials for layer 3 (first applied layer)
    k_emb<<<dim3(NG, NB), 256, 0, stream>>>(data, emb, fw2 + 3 * (size_t)NHID * NVEC,
                                            fb2 + 3 * (size_t)NVEC, bf, X, Upart, out);
    k_Ured<<<dim3(NB, 5), 256, 0, stream>>>(Upart, U);

    for (int i = NW - 1; i >= 1; --i) {
        k_apply<false><<<dim3(NG, NB), 256, 0, stream>>>(
            X, fw1 + (size_t)i * NDIM * NHID, fb1 + (size_t)i * NHID, U,
            fw2 + (size_t)(i - 1) * NHID * NVEC, fb2 + (size_t)(i - 1) * NVEC,
            Upart, nullptr, nullptr);
        k_Ured<<<dim3(NB, 5), 256, 0, stream>>>(Upart, U);
    }
    k_apply<true><<<dim3(NG, NB), 256, 0, stream>>>(
        X, fw1, fb1, U, nullptr, nullptr, nullptr, Wf, out);
}